// Round 6
// baseline (136.498 us; speedup 1.0000x reference)
//
#include <hip/hip_runtime.h>
#include <hip/hip_bf16.h>

#define B_TOT 16384

typedef __attribute__((ext_vector_type(8))) short short8;
typedef __attribute__((ext_vector_type(4))) short short4v;
typedef __attribute__((ext_vector_type(4))) float f32x4;

__device__ __forceinline__ float bf2f(short s){
  unsigned u = ((unsigned)(unsigned short)s) << 16;
  return __uint_as_float(u);
}
__device__ __forceinline__ unsigned f2bfu(float f){
  __hip_bfloat16 h = __float2bfloat16(f);
  return (unsigned)*reinterpret_cast<unsigned short*>(&h);
}
__device__ __forceinline__ short f2bf(float f){
  __hip_bfloat16 h = __float2bfloat16(f);
  return *reinterpret_cast<short*>(&h);
}

#define MFMA16(a,b,c) __builtin_amdgcn_mfma_f32_16x16x32_bf16(a,b,c,0,0,0)

// ---- d_ws layout (bf16 elements unless noted) ----
// Column-interleaved weight layout: for a GEMM whose wave w owns actual cols
// [32G, 32G+32): store B[(G*2+b)*16 + f][k] = W_actualcol(32G + 2f + b)[k].
// MFMA pair (even,odd) then yields ADJACENT output cols 2lm,2lm+1 -> u32 pack.
#define W_W1T   0        // [8][16][64]    enc_w1^T interleaved (C=128,K=64)
#define W_W2T   8192     // [8][16][128]   enc_w2^T interleaved (C=128,K=128)
#define W_GWT   24576    // [2][8][16][128] gat_w^T per head interleaved (C=128,K=128)
#define W_HW1T  57344    // [16][16][256]  rows: cols 0-127 val_w1^T, 128-255 pol_w1^T (C=256,K=256)
#define W_PW2T  122880   // [8][128]  pol_w2^T (plain)
#define W_VW2   123904   // [128]     val_w2 (plain)
#define W_NELEM 124032
#define CVEC_BYTE 248064 // f32 [4][128]: [2h+0]=gat_w@a1 (ei), [2h+1]=gat_w@a2 (ej)
#define PREP_TOT  124544

__global__ void prep_weights(const float* __restrict__ enc_w1, const float* __restrict__ enc_w2,
                             const float* __restrict__ gat_w, const float* __restrict__ gat_a,
                             const float* __restrict__ val_w1, const float* __restrict__ pol_w1,
                             const float* __restrict__ pol_w2, const float* __restrict__ val_w2,
                             unsigned short* __restrict__ wt, float* __restrict__ cvec){
  int t = blockIdx.x*256 + threadIdx.x;
  if (t >= PREP_TOT) return;
  if (t < W_NELEM){
    float v; int idx;
    if (t < 8192){                       // enc_w1t, C=128 K=64
      int c = t >> 6, k = t & 63;
      int G = c >> 5, r = c & 31, b = r & 1, f = r >> 1;
      idx = ((G*2 + b)*16 + f)*64 + k;
      v = enc_w1[k*128 + c];
    } else if (t < 24576){               // enc_w2t, C=128 K=128
      int u = t - 8192, c = u >> 7, k = u & 127;
      int G = c >> 5, r = c & 31, b = r & 1, f = r >> 1;
      idx = 8192 + ((G*2 + b)*16 + f)*128 + k;
      v = enc_w2[k*128 + c];
    } else if (t < 57344){               // gat_wt per head, C=128 K=128
      int u = t - 24576, h = u >> 14, r2 = u & 16383, o = r2 >> 7, d = r2 & 127;
      int G = o >> 5, r = o & 31, b = r & 1, f = r >> 1;
      idx = 24576 + h*16384 + ((G*2 + b)*16 + f)*128 + d;
      v = gat_w[h*16384 + d*128 + o];
    } else if (t < 122880){              // heads hidden, C=256 K=256
      int u = t - 57344, oc = u >> 8, k = u & 255;
      int G = oc >> 5, r = oc & 31, b = r & 1, f = r >> 1;
      idx = 57344 + ((G*2 + b)*16 + f)*256 + k;
      v = (oc < 128) ? val_w1[k*128 + oc] : pol_w1[k*128 + (oc - 128)];
    } else if (t < 123904){              // pol_w2^T plain
      int u = t - 122880, a = u >> 7, k = u & 127;
      idx = t;
      v = pol_w2[k*8 + a];
    } else {                             // val_w2 plain
      idx = t;
      v = val_w2[t - 123904];
    }
    wt[idx] = (unsigned short)f2bfu(v);
  } else {
    int q = t - W_NELEM;                 // 512 dots: cvec[vsel][d] = sum_o gat_w[h][d][o]*a[o]
    int vsel = q >> 7, d = q & 127;
    int h = vsel >> 1, s2 = vsel & 1;
    const float* gw = gat_w + h*16384 + d*128;
    const float* aa = gat_a + h*256 + s2*128;
    float s = 0.f;
    #pragma unroll 4
    for (int o = 0; o < 128; ++o) s += gw[o]*aa[o];
    cvec[vsel*128 + d] = s;
  }
}

// ---- fused main: 16 agents/block, 1024 blocks ----
// LDS: X [80][64]swz @0 (10240); h1 [80][128]swz @10240 (20480);
// emb [80][128]swz @0 (alias, barrier-guarded); mix [16][256]swz @20480 (8192);
// final [16][256]swz @0 (alias emb); H2 [16][256]swz @8192.
#define MIX_L   20480
#define FINAL_L 0
#define H2_L    8192
#define K_LDS   30720

__global__ __launch_bounds__(256, 4) void colight_fused(
    const float* __restrict__ obs, const float* __restrict__ nobs, const int* __restrict__ adjp,
    const float* __restrict__ enc_b1, const float* __restrict__ enc_b2,
    const float* __restrict__ val_b1, const float* __restrict__ val_b2,
    const float* __restrict__ pol_b1, const float* __restrict__ pol_b2,
    const unsigned short* __restrict__ wt_all, const float* __restrict__ cvec,
    float* __restrict__ dout)
{
  __shared__ __align__(16) char lds[K_LDS];
  const int tid  = threadIdx.x;
  const int lane = tid & 63;
  const int wv   = tid >> 6;
  const int lm   = lane & 15;
  const int grp  = lane >> 4;
  const int kb   = grp * 8;
  const int gblk = blockIdx.x * 16;

  const unsigned short* w1t  = wt_all + W_W1T;
  const unsigned short* w2t  = wt_all + W_W2T;
  const unsigned short* gwt  = wt_all + W_GWT;
  const unsigned short* hw1t = wt_all + W_HW1T;
  const unsigned short* pw2t = wt_all + W_PW2T;
  const unsigned short* vw2  = wt_all + W_VW2;

  // ---- stage X (80 x 64) f32 -> bf16 swz ----
  #pragma unroll
  for (int i = 0; i < 5; ++i){
    int chunk = i*256 + tid;
    int row = chunk >> 4;
    int c4  = (chunk & 15) * 4;
    int a = row/5, n = row%5;
    const float* src = n ? (nobs + ((size_t)(gblk+a)*4 + (n-1))*64 + c4)
                         : (obs  + (size_t)(gblk+a)*64 + c4);
    float4 v = *reinterpret_cast<const float4*>(src);
    short4v p = { f2bf(v.x), f2bf(v.y), f2bf(v.z), f2bf(v.w) };
    *reinterpret_cast<short4v*>(lds + ((row*128 + c4*2) ^ ((row & 7) << 4))) = p;
  }
  __syncthreads();

  // ---- GEMM1: X @ w1t -> h1 (relu+b1). wave owns actual cols [32wv,32wv+32) ----
  {
    f32x4 aE[5], aO[5];
    #pragma unroll
    for (int mt=0; mt<5; ++mt){ aE[mt]=(f32x4){0,0,0,0}; aO[mt]=(f32x4){0,0,0,0}; }
    #pragma unroll
    for (int ks=0; ks<2; ++ks){
      short8 bE = *reinterpret_cast<const short8*>(w1t + ((wv*2+0)*16 + lm)*64 + ks*32 + kb);
      short8 bO = *reinterpret_cast<const short8*>(w1t + ((wv*2+1)*16 + lm)*64 + ks*32 + kb);
      #pragma unroll
      for (int mt=0; mt<5; ++mt){
        int row = mt*16 + lm;
        short8 a = *reinterpret_cast<short8*>(lds + ((row*128 + (ks*32+kb)*2) ^ ((row&7)<<4)));
        aE[mt] = MFMA16(a, bE, aE[mt]);
        aO[mt] = MFMA16(a, bO, aO[mt]);
      }
    }
    const int ce = 32*wv + 2*lm;
    const float be = enc_b1[ce], bo = enc_b1[ce+1];
    #pragma unroll
    for (int mt=0; mt<5; ++mt)
      #pragma unroll
      for (int j=0; j<4; ++j){
        int row = mt*16 + grp*4 + j;
        unsigned pk = f2bfu(fmaxf(aE[mt][j] + be, 0.f))
                    | (f2bfu(fmaxf(aO[mt][j] + bo, 0.f)) << 16);
        *reinterpret_cast<unsigned*>(lds + 10240 + ((row*256 + ce*2) ^ ((row&7)<<4))) = pk;
      }
  }
  __syncthreads();

  // ---- GEMM2: h1 @ w2t + b2 -> emb ----
  {
    f32x4 aE[5], aO[5];
    #pragma unroll
    for (int mt=0; mt<5; ++mt){ aE[mt]=(f32x4){0,0,0,0}; aO[mt]=(f32x4){0,0,0,0}; }
    #pragma unroll
    for (int ks=0; ks<4; ++ks){
      short8 bE = *reinterpret_cast<const short8*>(w2t + ((wv*2+0)*16 + lm)*128 + ks*32 + kb);
      short8 bO = *reinterpret_cast<const short8*>(w2t + ((wv*2+1)*16 + lm)*128 + ks*32 + kb);
      #pragma unroll
      for (int mt=0; mt<5; ++mt){
        int row = mt*16 + lm;
        short8 a = *reinterpret_cast<short8*>(lds + 10240 + ((row*256 + (ks*32+kb)*2) ^ ((row&7)<<4)));
        aE[mt] = MFMA16(a, bE, aE[mt]);
        aO[mt] = MFMA16(a, bO, aO[mt]);
      }
    }
    __syncthreads();   // all h1 reads done before emb overwrites [0,20480)
    const int ce = 32*wv + 2*lm;
    const float be = enc_b2[ce], bo = enc_b2[ce+1];
    #pragma unroll
    for (int mt=0; mt<5; ++mt)
      #pragma unroll
      for (int j=0; j<4; ++j){
        int row = mt*16 + grp*4 + j;
        unsigned pk = f2bfu(aE[mt][j] + be) | (f2bfu(aO[mt][j] + bo) << 16);
        *reinterpret_cast<unsigned*>(lds + ((row*256 + ce*2) ^ ((row&7)<<4))) = pk;
      }
  }
  __syncthreads();

  // ---- attention + mix: one agent per 16-lane group -> mix [16][256] LDS ----
  {
    const int ag = wv*4 + grp;
    const int ga = gblk + ag;
    float ef[5][8];
    #pragma unroll
    for (int n=0; n<5; ++n){
      int row = ag*5 + n;
      short8 er = *reinterpret_cast<short8*>(lds + ((row*256 + lm*16) ^ ((row&7)<<4)));
      #pragma unroll
      for (int e=0; e<8; ++e) ef[n][e] = bf2f(er[e]);
    }
    int msk[5];
    #pragma unroll
    for (int n=0; n<5; ++n) msk[n] = adjp[(size_t)ga*5 + n];

    #pragma unroll
    for (int h=0; h<2; ++h){
      float c1v[8], c2v[8];
      #pragma unroll
      for (int e=0; e<8; ++e){
        c1v[e] = cvec[(2*h  )*128 + lm*8 + e];
        c2v[e] = cvec[(2*h+1)*128 + lm*8 + e];
      }
      float ei = 0.f;
      #pragma unroll
      for (int e=0; e<8; ++e) ei += ef[0][e]*c1v[e];
      ei += __shfl_xor(ei,1); ei += __shfl_xor(ei,2); ei += __shfl_xor(ei,4); ei += __shfl_xor(ei,8);

      float at[5]; float mx = -1e30f;
      #pragma unroll
      for (int n=0; n<5; ++n){
        float t = 0.f;
        #pragma unroll
        for (int e=0; e<8; ++e) t += ef[n][e]*c2v[e];
        t += __shfl_xor(t,1); t += __shfl_xor(t,2); t += __shfl_xor(t,4); t += __shfl_xor(t,8);
        float s = ei + t;
        s = (s > 0.f) ? s : 0.2f*s;
        at[n] = s;
        if (msk[n] && s > mx) mx = s;
      }
      float den = 0.f;
      #pragma unroll
      for (int n=0; n<5; ++n){
        float e2 = msk[n] ? __expf(at[n]-mx) : 0.f;
        at[n] = e2; den += e2;
      }
      float inv = 1.f/den;
      short8 o;
      #pragma unroll
      for (int e=0; e<8; ++e){
        float s = 0.f;
        #pragma unroll
        for (int n=0; n<5; ++n) s += at[n]*ef[n][e];
        o[e] = f2bf(s*inv);
      }
      *reinterpret_cast<short8*>(lds + MIX_L + ((ag*512 + (h*128 + lm*8)*2) ^ ((ag&7)<<4))) = o;
    }
  }
  __syncthreads();

  // ---- mix-GEMM: final[., h*128+o] = mix[., h-slice] @ gat_w[h]^T ----
  {
    const int hh = wv >> 1, half = wv & 1;
    f32x4 fE[2], fO[2];
    #pragma unroll
    for (int g2=0; g2<2; ++g2){ fE[g2]=(f32x4){0,0,0,0}; fO[g2]=(f32x4){0,0,0,0}; }
    #pragma unroll
    for (int ks=0; ks<4; ++ks){
      short8 a = *reinterpret_cast<short8*>(lds + MIX_L + ((lm*512 + (hh*128 + ks*32 + kb)*2) ^ ((lm&7)<<4)));
      #pragma unroll
      for (int g2=0; g2<2; ++g2){
        int G = half*2 + g2;
        short8 bE = *reinterpret_cast<const short8*>(gwt + hh*16384 + ((G*2+0)*16 + lm)*128 + ks*32 + kb);
        short8 bO = *reinterpret_cast<const short8*>(gwt + hh*16384 + ((G*2+1)*16 + lm)*128 + ks*32 + kb);
        fE[g2] = MFMA16(a, bE, fE[g2]);
        fO[g2] = MFMA16(a, bO, fO[g2]);
      }
    }
    #pragma unroll
    for (int g2=0; g2<2; ++g2){
      int cb = hh*128 + half*64 + 32*g2 + 2*lm;
      #pragma unroll
      for (int j=0; j<4; ++j){
        int row = grp*4 + j;
        unsigned pk = f2bfu(fE[g2][j]) | (f2bfu(fO[g2][j]) << 16);
        *reinterpret_cast<unsigned*>(lds + FINAL_L + ((row*512 + cb*2) ^ ((row&7)<<4))) = pk;
      }
    }
  }
  __syncthreads();

  // ---- heads GEMM: H2 = relu(final @ hw1t + b). wave owns cols [64wv,64wv+64) ----
  {
    f32x4 hE[2], hO[2];
    #pragma unroll
    for (int g2=0; g2<2; ++g2){ hE[g2]=(f32x4){0,0,0,0}; hO[g2]=(f32x4){0,0,0,0}; }
    #pragma unroll
    for (int ks=0; ks<8; ++ks){
      short8 a = *reinterpret_cast<short8*>(lds + FINAL_L + ((lm*512 + (ks*32+kb)*2) ^ ((lm&7)<<4)));
      #pragma unroll
      for (int g2=0; g2<2; ++g2){
        int G = 2*wv + g2;
        short8 bE = *reinterpret_cast<const short8*>(hw1t + ((G*2+0)*16 + lm)*256 + ks*32 + kb);
        short8 bO = *reinterpret_cast<const short8*>(hw1t + ((G*2+1)*16 + lm)*256 + ks*32 + kb);
        hE[g2] = MFMA16(a, bE, hE[g2]);
        hO[g2] = MFMA16(a, bO, hO[g2]);
      }
    }
    #pragma unroll
    for (int g2=0; g2<2; ++g2){
      int oc = 64*wv + 32*g2 + 2*lm;
      float be = (oc   < 128) ? val_b1[oc]   : pol_b1[oc-128];
      float bo = (oc+1 < 128) ? val_b1[oc+1] : pol_b1[oc-127];
      #pragma unroll
      for (int j=0; j<4; ++j){
        int row = grp*4 + j;
        unsigned pk = f2bfu(fmaxf(hE[g2][j] + be, 0.f))
                    | (f2bfu(fmaxf(hO[g2][j] + bo, 0.f)) << 16);
        *reinterpret_cast<unsigned*>(lds + H2_L + ((row*512 + oc*2) ^ ((row&7)<<4))) = pk;
      }
    }
  }
  __syncthreads();

  // ---- projections ----
  if (tid < 128){
    int a = tid >> 3, act = tid & 7;
    float s = pol_b2[act];
    #pragma unroll
    for (int i=0; i<16; ++i){
      short8 v = *reinterpret_cast<short8*>(lds + H2_L + ((a*512 + (128 + i*8)*2) ^ ((a&7)<<4)));
      short8 w = *reinterpret_cast<const short8*>(pw2t + act*128 + i*8);
      #pragma unroll
      for (int e=0; e<8; ++e) s += bf2f(v[e]) * bf2f(w[e]);
    }
    dout[B_TOT + (size_t)(gblk + a)*8 + act] = s;
  } else if (tid < 160){
    int q = tid - 128, a = q >> 1, hf = q & 1;
    float s = 0.f;
    #pragma unroll
    for (int i=0; i<8; ++i){
      short8 v = *reinterpret_cast<short8*>(lds + H2_L + ((a*512 + (hf*64 + i*8)*2) ^ ((a&7)<<4)));
      short8 w = *reinterpret_cast<const short8*>(vw2 + hf*64 + i*8);
      #pragma unroll
      for (int e=0; e<8; ++e) s += bf2f(v[e]) * bf2f(w[e]);
    }
    s += __shfl_xor(s, 1);
    if (!hf) dout[gblk + a] = s + val_b2[0];
  }
}

extern "C" void kernel_launch(void* const* d_in, const int* in_sizes, int n_in,
                              void* d_out, int out_size, void* d_ws, size_t ws_size,
                              hipStream_t stream) {
  (void)in_sizes; (void)n_in; (void)out_size; (void)ws_size;
  const float* obs    = (const float*)d_in[0];
  const float* nobs   = (const float*)d_in[1];
  const int*   adj    = (const int*)  d_in[2];
  const float* enc_w1 = (const float*)d_in[3];
  const float* enc_b1 = (const float*)d_in[4];
  const float* enc_w2 = (const float*)d_in[5];
  const float* enc_b2 = (const float*)d_in[6];
  const float* gat_w  = (const float*)d_in[7];
  const float* gat_a  = (const float*)d_in[8];
  const float* val_w1 = (const float*)d_in[9];
  const float* val_b1 = (const float*)d_in[10];
  const float* val_w2 = (const float*)d_in[11];
  const float* val_b2 = (const float*)d_in[12];
  const float* pol_w1 = (const float*)d_in[13];
  const float* pol_b1 = (const float*)d_in[14];
  const float* pol_w2 = (const float*)d_in[15];
  const float* pol_b2 = (const float*)d_in[16];

  unsigned short* wt   = (unsigned short*)d_ws;
  float*          cvec = (float*)((char*)d_ws + CVEC_BYTE);

  prep_weights<<<(PREP_TOT + 255)/256, 256, 0, stream>>>(
      enc_w1, enc_w2, gat_w, gat_a, val_w1, pol_w1, pol_w2, val_w2, wt, cvec);

  colight_fused<<<B_TOT/16, 256, 0, stream>>>(
      obs, nobs, adj, enc_b1, enc_b2,
      val_b1, val_b2, pol_b1, pol_b2,
      wt, cvec, (float*)d_out);
}